// Round 3
// baseline (501.905 us; speedup 1.0000x reference)
//
#include <hip/hip_runtime.h>

#define NPTS 131072
// transposed feature region offsets (elements, fp32) in ws feature area:
//   scale0: 56*56*64 = 200704, scale1: 28*28*128 = 100352,
//   scale2: 14*14*256 = 50176, scale3: 7*7*512 = 25088  -> total 376320
#define FT_TOTAL 376320

// grid-stride gather geometry: stride MUST be a multiple of 240 so each
// thread's chunk-within-row j is loop-invariant.
//   3840 blocks * 256 thr = 983040 chunks/iter = 4096 rows/iter
//   total chunks = NPTS*240 = 31457280 = 32 iterations exactly
#define GATHER_BLOCKS 3840
#define GATHER_ITERS  32
#define ROWS_PER_ITER 4096

typedef float f32x4 __attribute__((ext_vector_type(4)));

// ------------------------------------------------------------------
// Kernel 1 (fused prep): blocks [0,512) compute per-point projection
// indices (numerics IDENTICAL to the verified absmax==0.0 version);
// blocks [512,1982) transpose feat[b] [C,H,W] -> [H*W, C] so the
// per-point channel gather is contiguous. Both halves are exact
// multiples of 256 threads: no tail checks, block-uniform branch.
// ------------------------------------------------------------------
__global__ __launch_bounds__(256) void k_prep(
    const float* __restrict__ pts,
    int4* __restrict__ idx4,
    const float* __restrict__ f0,
    const float* __restrict__ f1,
    const float* __restrict__ f2,
    const float* __restrict__ f3,
    const int* __restrict__ batch,
    float* __restrict__ ft)
{
    int blk = blockIdx.x;
    if (blk < 512) {
        // ---- projection indices ----
        int n = blk * 256 + threadIdx.x;
        float px = pts[3 * n + 0];
        float py = pts[3 * n + 1];
        float pz = pts[3 * n + 2];
        float qh = __fdiv_rn(py, pz);
        float qw = __fdiv_rn(px, -pz);
        float h = __fadd_rn(__fmul_rn(248.0f, qh), 111.5f);
        float w = __fadd_rn(__fmul_rn(248.0f, qw), 111.5f);
        h = fminf(fmaxf(h, 0.0f), 223.0f);
        w = fminf(fmaxf(w, 0.0f), 223.0f);

        const float scl[4] = {0.25f, 0.125f, 0.0625f, 0.03125f}; // exact pow2
        const int   S[4]   = {56, 28, 14, 7};
        int r[4];
#pragma unroll
        for (int s = 0; s < 4; ++s) {
            float x = h * scl[s];
            float y = w * scl[s];
            int x1 = (int)floorf(x);
            int x2 = min((int)ceilf(x), S[s] - 1);
            int y1 = (int)floorf(y);
            int y2 = min((int)ceilf(y), S[s] - 1);
            int bit = (x2 - x1) * (y2 - y1);   // 0 or 1 (trunc==floor, x>=0)
            r[s] = bit ? (x1 * S[s] + y1) : -1;
        }
        idx4[n] = make_int4(r[0], r[1], r[2], r[3]);
    } else {
        // ---- feature transpose [C,H,W] -> [H*W, C] ----
        int d = (blk - 512) * 256 + threadIdx.x;   // < FT_TOTAL exactly
        int b = *batch;
        const float* src;
        int local, c, p, hw;
        if (d < 200704) {
            local = d;          c = local & 63;  p = local >> 6; hw = 3136;
            src = f0 + (size_t)b * 64 * 3136;
        } else if (d < 301056) {
            local = d - 200704; c = local & 127; p = local >> 7; hw = 784;
            src = f1 + (size_t)b * 128 * 784;
        } else if (d < 351232) {
            local = d - 301056; c = local & 255; p = local >> 8; hw = 196;
            src = f2 + (size_t)b * 256 * 196;
        } else {
            local = d - 351232; c = local & 511; p = local >> 9; hw = 49;
            src = f3 + (size_t)b * 512 * 49;
        }
        ft[d] = src[c * hw + p];   // scattered read (L2/L3 absorbs), coalesced write
    }
}

// ------------------------------------------------------------------
// Kernel 2: the writer, PERSISTENT GRID-STRIDE (the fill kernel's own
// shape). 3840 blocks (15/CU), each thread streams 32 float4 chunks at
// stride 983040 chunks. Because the stride is a multiple of 240, the
// chunk-within-row j (and hence scale s, channel base, table offset)
// is computed ONCE per thread; the loop body is just
//   {scalar idx load, predicated 16B ft load, 16B linear store, ptr adds}.
// Stores remain perfectly coalesced (consecutive lanes -> consecutive
// 16B; out float4-index == chunk id). unroll 4 = 4 independent
// load->store chains in flight per thread.
// ------------------------------------------------------------------
__global__ __launch_bounds__(256) void k_gather(
    const int* __restrict__ idx,     // [N][4]
    const float* __restrict__ ft,    // transposed feats (L2-resident)
    float* __restrict__ out)         // [N, 960]
{
    int t = blockIdx.x * 256 + threadIdx.x;     // chunk id at iteration 0
    int n0 = t / 240;                           // once: magic mul
    int j  = t - n0 * 240;                      // loop-invariant chunk-in-row

    int s, C, toff, cb;
    if (j < 16)       { s = 0; C = 64;  toff = 0;      cb = j * 4; }
    else if (j < 48)  { s = 1; C = 128; toff = 200704; cb = (j - 16) * 4; }
    else if (j < 112) { s = 2; C = 256; toff = 301056; cb = (j - 48) * 4; }
    else              { s = 3; C = 512; toff = 351232; cb = (j - 112) * 4; }

    const int*   ip = idx + n0 * 4 + s;         // +4096 rows per iter
    const float* fb = ft + toff + cb;           // + id*C per access
    f32x4*       op = (f32x4*)out + t;          // linear store stream

#pragma unroll 4
    for (int it = 0; it < GATHER_ITERS; ++it) {
        int id = *ip;
        f32x4 v = (f32x4)(0.0f);
        if (id >= 0)
            v = *(const f32x4*)(fb + id * C);   // coalesced L2 hit (7% of rows)
        *op = v;
        ip += ROWS_PER_ITER * 4;
        op += GATHER_BLOCKS * 256;
    }
}

extern "C" void kernel_launch(void* const* d_in, const int* in_sizes, int n_in,
                              void* d_out, int out_size, void* d_ws, size_t ws_size,
                              hipStream_t stream) {
    const float* f0  = (const float*)d_in[0];
    const float* f1  = (const float*)d_in[1];
    const float* f2  = (const float*)d_in[2];
    const float* f3  = (const float*)d_in[3];
    const float* pts = (const float*)d_in[4];
    const int* batch = (const int*)d_in[5];

    // ws layout: [ int4 idx[NPTS] : 2 MiB ][ f32 ft[FT_TOTAL] : 1.44 MiB ]
    int4* idx4 = (int4*)d_ws;
    float* ft = (float*)((char*)d_ws + (size_t)NPTS * 16);
    float* out = (float*)d_out;

    // 512 index blocks + 1470 transpose blocks, one launch
    k_prep<<<512 + 1470, 256, 0, stream>>>(pts, idx4, f0, f1, f2, f3, batch, ft);
    // persistent gather: 3840 blocks, 32 strided chunks per thread
    k_gather<<<GATHER_BLOCKS, 256, 0, stream>>>((const int*)idx4, ft, out);
}